// Round 7
// baseline (1216.002 us; speedup 1.0000x reference)
//
#include <hip/hip_runtime.h>
#include <hip/hip_bf16.h>
#include <stdint.h>

#define B_ 32
#define T_ 128
#define H_ 1024
#define V_ 32000
#define NBLK_REC 64

typedef unsigned short u16;
typedef __attribute__((ext_vector_type(8))) short short8;
typedef __attribute__((ext_vector_type(4))) float f32x4;

static __device__ __forceinline__ u16 f2bf(float f) {
    uint32_t u = __float_as_uint(f);
    uint32_t r = (u + 0x7FFFu + ((u >> 16) & 1u)) >> 16;
    return (u16)r;
}

static __device__ __forceinline__ float sigmf(float x) {
    return 1.0f / (1.0f + __expf(-x));
}

static __device__ __forceinline__ float tanh_f(float x) {
    x = fminf(fmaxf(x, -20.f), 20.f);
    float e = __expf(2.f * x);
    return (e - 1.f) / (e + 1.f);
}

// Direct global->LDS 16B copy (dest is wave-uniform base + lane*16 in HW).
static __device__ __forceinline__ void gload16(const void* g, void* l) {
    __builtin_amdgcn_global_load_lds(
        (const __attribute__((address_space(1))) uint32_t*)g,
        (__attribute__((address_space(3))) uint32_t*)(uint32_t)(uintptr_t)l,
        16, 0, 0);
}

// ---------------------------------------------------------------------------
// Prep: W_comb = W_ih[:,1:] + W_hh  (bf16), wx = W_ih[:,0], biasc = b_ih+b_hh
// Also zeroes the 512 producer sub-flags (re-zeroed every launch/replay).
// ---------------------------------------------------------------------------
__global__ void prep_w(const float* __restrict__ Wih, const float* __restrict__ Whh,
                       const float* __restrict__ bih, const float* __restrict__ bhh,
                       u16* __restrict__ Wc, float* __restrict__ wx, float* __restrict__ biasc,
                       unsigned* __restrict__ flags) {
    int idx = blockIdx.x * 256 + threadIdx.x;      // 4096*1024 threads
    int r = idx >> 10, k = idx & 1023;
    float v = Wih[r * (H_ + 1) + 1 + k] + Whh[idx];
    Wc[idx] = f2bf(v);
    if (k == 0) {
        wx[r] = Wih[r * (H_ + 1)];
        biasc[r] = bih[r] + bhh[r];
    }
    if (idx < 512) flags[idx] = 0u;
}

// ---------------------------------------------------------------------------
// Init: h0 = enc @ W_h^T (bf16), c0 = enc @ W_c^T (fp32).
// One wave per (sel, j) row; W-row held in registers, reused for all 32 b.
// ---------------------------------------------------------------------------
__global__ void init_hc(const float* __restrict__ enc, const float* __restrict__ Wh,
                        const float* __restrict__ Wcp, u16* __restrict__ h0,
                        float* __restrict__ c0) {
    int gwid = blockIdx.x * 4 + (threadIdx.x >> 6);   // 2048 waves
    int lane = threadIdx.x & 63;
    int sel = gwid >> 10;                // 0: h, 1: c
    int j = gwid & 1023;
    const float* W = sel ? Wcp : Wh;
    const float* wrow = W + (size_t)j * H_;
    f32x4 wv[4];
#pragma unroll
    for (int it = 0; it < 4; ++it)
        wv[it] = *(const f32x4*)(wrow + it * 256 + lane * 4);
#pragma unroll 2
    for (int b = 0; b < B_; ++b) {
        const float* erow = enc + (size_t)b * H_;
        float acc = 0.f;
#pragma unroll
        for (int it = 0; it < 4; ++it) {
            f32x4 ev = *(const f32x4*)(erow + it * 256 + lane * 4);
            acc += wv[it][0] * ev[0] + wv[it][1] * ev[1] + wv[it][2] * ev[2] + wv[it][3] * ev[3];
        }
#pragma unroll
        for (int s = 32; s >= 1; s >>= 1) acc += __shfl_xor(acc, s, 64);
        if (lane == 0) {
            if (sel) c0[(size_t)b * H_ + j] = acc;
            else     h0[(size_t)b * H_ + j] = f2bf(acc);
        }
    }
}

// ---------------------------------------------------------------------------
// Fused persistent kernel, 256 blocks x 512 threads.
//  - Blocks 0..63: LSTM recurrence (block owns j0=bid*16; weights resident in
//    AGPR/VGPR; wave-autonomous sub-flag sync).
//  - Blocks 64..255: W_out fp32->bf16 conversion on the otherwise-idle CUs.
// Sub-flag protocol: producer wave w' computes h for its OWN 2 j-columns
// (lane=(delta,b)), stores them (agent scope), drains ITS OWN vmcnt, then
// releases flags[bid*8+w']. Consumer wave w (k-slice [128w,128w+128)) polls
// the 64 contiguous sub-flags of blocks 8w..8w+7 (one coalesced load/poll).
// No block barrier on the release path.
// ---------------------------------------------------------------------------
__global__ __launch_bounds__(512, 1) void lstm_fused(
    const u16* __restrict__ Wc, const float* __restrict__ wx,
    const float* __restrict__ biasc, const u16* __restrict__ h0,
    const float* __restrict__ c0, const float* __restrict__ y,
    u16* __restrict__ A, unsigned* __restrict__ flags,
    const float* __restrict__ Wout, u16* __restrict__ Wo) {
    __shared__ float red[8][64 * 33];    // 8 K-wave partials, padded
    __shared__ float cs[16][33];         // cell state [jlx][b], padded
    __shared__ float wxs[64], bcs[64];   // per-row x-weight / bias
    __shared__ float ys[32 * 129];       // y staged, padded stride 129

    int tid = threadIdx.x;

    if (blockIdx.x >= NBLK_REC) {
        // ---- converter role: Wo = bf16(Wout), grid-stride over quads ----
        const int nconv = (256 - NBLK_REC) * 512;
        int idx = (blockIdx.x - NBLK_REC) * 512 + tid;
        const int nquad = V_ * H_ / 4;   // 8,192,000
        for (int i = idx; i < nquad; i += nconv) {
            f32x4 v = *(const f32x4*)(Wout + (size_t)i * 4);
            uint2 o;
            o.x = (uint32_t)f2bf(v[0]) | ((uint32_t)f2bf(v[1]) << 16);
            o.y = (uint32_t)f2bf(v[2]) | ((uint32_t)f2bf(v[3]) << 16);
            *(uint2*)(Wo + (size_t)i * 4) = o;
        }
        return;
    }

    int lane = tid & 63;
    int w = tid >> 6;                    // wave id 0..7: K-slice w*128 AND j-cols 2w,2w+1
    int bid = blockIdx.x;
    int j0 = bid * 16;
    int jl = lane & 15;                  // MFMA A-row / B-col lane index
    int kc = (lane >> 4) * 8;            // k-offset within 32-chunk
    int delta = lane >> 5, b = lane & 31;
    int jlx = 2 * w + delta;             // this thread's j column (pointwise)

    // ---- one-time: weights to registers (resident; AGPR ok), pinned ----
    short8 afr[4][4];
    {
        const u16* abase = Wc + (size_t)(j0 + jl) * H_ + w * 128 + kc;
#pragma unroll
        for (int g = 0; g < 4; ++g)
#pragma unroll
            for (int ks = 0; ks < 4; ++ks)
                afr[g][ks] = *(const short8*)(abase + (size_t)g * H_ * H_ + ks * 32);
    }
#pragma unroll
    for (int g = 0; g < 4; ++g)
#pragma unroll
        for (int ks = 0; ks < 4; ++ks)
            asm volatile("" : "+v"(afr[g][ks]));   // pin: defeat remat/reload

    // ---- one-time: stage wx/bias/y/c0 into LDS ----
    if (tid < 64) {
        int g = tid >> 4, q = tid & 15;
        wxs[tid] = wx[(size_t)g * H_ + j0 + q];
        bcs[tid] = biasc[(size_t)g * H_ + j0 + q];
    }
#pragma unroll
    for (int i = tid; i < B_ * T_; i += 512)
        ys[(i >> 7) * 129 + (i & 127)] = y[i];
    cs[jlx][b] = c0[(size_t)b * H_ + j0 + jlx];
    __syncthreads();

    for (int t = 0; t < T_; ++t) {
        const u16* hp = (t == 0) ? h0 : (A + (size_t)(t - 1) * B_ * H_);

        // ---- per-wave slice wait: 64 sub-flags of blocks 8w..8w+7 ----
        if (t > 0) {
            const unsigned* fp = &flags[(w << 6) + lane];
            unsigned target = (unsigned)t;
            int guard = 0;
            for (;;) {
                unsigned v = __hip_atomic_load(fp, __ATOMIC_RELAXED, __HIP_MEMORY_SCOPE_AGENT);
                if (__all(v >= target)) break;
                if (++guard > 20000000) break;   // hang-safety; never triggers co-resident
            }
            __atomic_signal_fence(__ATOMIC_ACQUIRE);
        }

        // ---- load h b-frags for this wave's k-slice and MFMA ----
        short8 bfr0[4], bfr1[4];
        {
            const u16* hb = hp + (size_t)jl * H_ + w * 128 + kc;
#pragma unroll
            for (int ks = 0; ks < 4; ++ks) {
                bfr0[ks] = *(const short8*)(hb + ks * 32);
                bfr1[ks] = *(const short8*)(hb + (size_t)16 * H_ + ks * 32);
            }
        }
        f32x4 acc[4][2] = {};
#pragma unroll
        for (int ks = 0; ks < 4; ++ks) {
#pragma unroll
            for (int g = 0; g < 4; ++g) {
                acc[g][0] = __builtin_amdgcn_mfma_f32_16x16x32_bf16(afr[g][ks], bfr0[ks], acc[g][0], 0, 0, 0);
                acc[g][1] = __builtin_amdgcn_mfma_f32_16x16x32_bf16(afr[g][ks], bfr1[ks], acc[g][1], 0, 0, 0);
            }
        }
        // ---- partials to LDS ----
        int r0 = (lane >> 4) * 4;
#pragma unroll
        for (int g = 0; g < 4; ++g)
#pragma unroll
            for (int bt = 0; bt < 2; ++bt)
#pragma unroll
                for (int r = 0; r < 4; ++r)
                    red[w][(g * 16 + r0 + r) * 33 + bt * 16 + jl] = acc[g][bt][r];
        __syncthreads();   // red RAW: all partials visible

        // ---- pointwise for THIS wave's 2 j-columns; store; own drain; flag --
        {
            float yv = ys[b * 129 + t];
            float pg[4];
#pragma unroll
            for (int g = 0; g < 4; ++g) {
                int row = (g * 16 + jlx) * 33 + b;
                float sum = red[0][row];
#pragma unroll
                for (int ww = 1; ww < 8; ++ww) sum += red[ww][row];
                pg[g] = sum + wxs[g * 16 + jlx] * yv + bcs[g * 16 + jlx];
            }
            float iv = sigmf(pg[0]);
            float fv = sigmf(pg[1]);
            float gv = tanh_f(pg[2]);
            float ov = sigmf(pg[3]);
            float cv = fv * cs[jlx][b] + iv * gv;
            cs[jlx][b] = cv;
            float hv = ov * tanh_f(cv);

            unsigned hb16 = (unsigned)f2bf(hv);
            unsigned oth = (unsigned)__shfl((int)hb16, lane + 32, 64); // odd-j partner
            if (delta == 0) {
                uint32_t pk = hb16 | (oth << 16);
                __hip_atomic_store((uint32_t*)(A + ((size_t)t * B_ + b) * H_ + j0 + 2 * w),
                                   pk, __ATOMIC_RELAXED, __HIP_MEMORY_SCOPE_AGENT);
            }
            asm volatile("s_waitcnt vmcnt(0)" ::: "memory");   // own stores at coherence pt
            if (lane == 0)
                __hip_atomic_store(&flags[bid * 8 + w], (unsigned)(t + 1),
                                   __ATOMIC_RELAXED, __HIP_MEMORY_SCOPE_AGENT);
        }
        __syncthreads();   // red WAR: all reads done before next-step writes
    }
}

// ---------------------------------------------------------------------------
// Output GEMM: C[row][n] = sum_k A[t][b][k] * Wo[n][k] + b_out[n]
// A layout is [t][b][j] (t-major). m-tile = batch mb; tile rows = t 0..127.
// 128x128 tile, BK=32, DOUBLE-BUFFERED global_load_lds staging (stage k+1
// during MFMA k, one barrier per K-step), XCD-bijective swizzle. Epilogue
// transposes C through LDS -> contiguous 512B t-rows.
// ---------------------------------------------------------------------------
#define TRS 132   // transpose-buffer row stride in words (528B)
__global__ __launch_bounds__(256) void gemm_out(
    const u16* __restrict__ A, const u16* __restrict__ Wo,
    const float* __restrict__ bout, float* __restrict__ out) {
    __shared__ __align__(16) uint8_t smem[32768];   // 2 bufs x (As 8KB + Bs 8KB); tr aliases
    u16* sb = (u16*)smem;
    float* tr = (float*)smem;           // epilogue transpose buffer (16.9KB)

    int orig = blockIdx.x;                       // 8000 = 8 XCDs * 1000
    int w = (orig & 7) * 1000 + (orig >> 3);     // bijective XCD chunking
    int mb = w & 31;                             // m-block == batch b
    int nb = w >> 5;                             // 250 n-blocks
    int n0 = nb * 128;

    int tid = threadIdx.x, lane = tid & 63, wid = tid >> 6;
    int wm = wid >> 1, wn = wid & 1;

    f32x4 acc[4][4] = {};

    int srow = tid >> 2;            // 0..63 (= t index)
    int scol = (tid & 3) * 8;       // k-offset within 32-chunk
    const u16* Ag = A + ((size_t)srow * B_ + mb) * H_ + scol;    // A[t][mb][k]
    const u16* Bg = Wo + (size_t)(n0 + srow) * H_ + scol;

    int kc = (lane >> 4) * 8;
    int frow = lane & 15;

    // buffer layout (u16 offsets within sb): buf*8192 + {As0:0, As1:2048, Bs0:4096, Bs1:6144}
    // prologue: stage tile 0 into buf 0
    {
        gload16(Ag, sb + tid * 8);
        gload16(Ag + (size_t)64 * B_ * H_, sb + 2048 + tid * 8);
        gload16(Bg, sb + 4096 + tid * 8);
        gload16(Bg + (size_t)64 * H_, sb + 6144 + tid * 8);
    }
    __syncthreads();   // implicit vmcnt(0): tile 0 staged

    for (int ks = 0; ks < 32; ++ks) {
        int cur = ks & 1;
        if (ks < 31) {   // stage next tile into other buffer (overlaps MFMA)
            int nxt = (ks + 1) & 1;
            int k1 = (ks + 1) * 32;
            u16* db = sb + nxt * 8192 + tid * 8;
            gload16(Ag + k1, db);
            gload16(Ag + (size_t)64 * B_ * H_ + k1, db + 2048);
            gload16(Bg + k1, db + 4096);
            gload16(Bg + (size_t)64 * H_ + k1, db + 6144);
        }
        const u16* Asb = sb + cur * 8192;
        const u16* Bsb = Asb + 4096;
        short8 af[4], bf[4];
#pragma unroll
        for (int mt = 0; mt < 4; ++mt)
            af[mt] = *(const short8*)(&Asb[(wm * 64 + mt * 16 + frow) * 32 + kc]);
#pragma unroll
        for (int nt = 0; nt < 4; ++nt)
            bf[nt] = *(const short8*)(&Bsb[(wn * 64 + nt * 16 + frow) * 32 + kc]);
#pragma unroll
        for (int mt = 0; mt < 4; ++mt)
#pragma unroll
            for (int nt = 0; nt < 4; ++nt)
                acc[mt][nt] = __builtin_amdgcn_mfma_f32_16x16x32_bf16(af[mt], bf[nt], acc[mt][nt], 0, 0, 0);
        __syncthreads();   // drains vmcnt(0)+lgkm: next tile staged, reads done
    }

    // ---- epilogue: bias + transpose through LDS, coalesced t-major stores --
    float biasv[4];
#pragma unroll
    for (int nt = 0; nt < 4; ++nt)
        biasv[nt] = bout[n0 + wn * 64 + nt * 16 + (lane & 15)];

    int b = mb;
#pragma unroll
    for (int p = 0; p < 4; ++p) {
        __syncthreads();   // previous pass reads done
        if (wn == (p >> 1)) {
#pragma unroll
            for (int hh = 0; hh < 2; ++hh) {
                int nt = (p & 1) * 2 + hh;
                int nl = ((nt & 1) << 4) + (lane & 15);   // row within 32-group
#pragma unroll
                for (int mt = 0; mt < 4; ++mt) {
                    f32x4 v = acc[mt][nt];
                    float bs = biasv[nt];
                    v[0] += bs; v[1] += bs; v[2] += bs; v[3] += bs;
                    int t = wm * 64 + mt * 16 + ((lane >> 4) << 2);
                    *(f32x4*)&tr[nl * TRS + t] = v;
                }
            }
        }
        __syncthreads();
        {
            int row = tid >> 3;              // 0..31
            int c0 = (tid & 7) * 16;         // float offset within t-row
            int n = n0 + p * 32 + row;
            float* dst = out + ((size_t)b * V_ + n) * T_ + c0;
            const float* srcp = &tr[row * TRS + c0];
            f32x4 v0 = *(const f32x4*)(srcp);
            f32x4 v1 = *(const f32x4*)(srcp + 4);
            f32x4 v2 = *(const f32x4*)(srcp + 8);
            f32x4 v3 = *(const f32x4*)(srcp + 12);
            *(f32x4*)(dst)      = v0;
            *(f32x4*)(dst + 4)  = v1;
            *(f32x4*)(dst + 8)  = v2;
            *(f32x4*)(dst + 12) = v3;
        }
    }
}

// ---------------------------------------------------------------------------
extern "C" void kernel_launch(void* const* d_in, const int* in_sizes, int n_in,
                              void* d_out, int out_size, void* d_ws, size_t ws_size,
                              hipStream_t stream) {
    const float* y    = (const float*)d_in[0];   // [B,T]
    const float* enc  = (const float*)d_in[1];   // [B,H]
    const float* Wh   = (const float*)d_in[2];   // [H,H]
    const float* Wcp  = (const float*)d_in[3];   // [H,H]
    const float* Wih  = (const float*)d_in[4];   // [4H,1+H]
    const float* Whh  = (const float*)d_in[5];   // [4H,H]
    const float* bih  = (const float*)d_in[6];   // [4H]
    const float* bhh  = (const float*)d_in[7];   // [4H]
    const float* Wout = (const float*)d_in[8];   // [V,H]
    const float* bout = (const float*)d_in[9];   // [V]

    uint8_t* ws = (uint8_t*)d_ws;
    u16*  Wcomb = (u16*)ws;                                   // 4096*1024*2  = 8,388,608
    u16*  Wo    = (u16*)(ws + 8388608);                       // 32000*1024*2 = 65,536,000
    float* wx    = (float*)(ws + 8388608 + 65536000);         // 4096*4
    float* biasc = wx + 4096;                                 // 4096*4
    u16*  h0    = (u16*)(biasc + 4096);                       // 32*1024*2
    float* c     = (float*)(h0 + 32 * 1024);                  // 32*1024*4
    u16*  A     = (u16*)(c + 32 * 1024);                      // [T][B][H] bf16
    unsigned* flags = (unsigned*)(A + (size_t)4096 * 1024);   // 512*4 B

    prep_w<<<16384, 256, 0, stream>>>(Wih, Whh, bih, bhh, Wcomb, wx, biasc, flags);
    init_hc<<<512, 256, 0, stream>>>(enc, Wh, Wcp, h0, c);

    lstm_fused<<<256, 512, 0, stream>>>(Wcomb, wx, biasc, h0, c, y, A, flags, Wout, Wo);

    gemm_out<<<8000, 256, 0, stream>>>(A, Wo, bout, (float*)d_out);
}

// Round 8
// 1206.112 us; speedup vs baseline: 1.0082x; 1.0082x over previous
//
#include <hip/hip_runtime.h>
#include <hip/hip_bf16.h>
#include <stdint.h>

#define B_ 32
#define T_ 128
#define H_ 1024
#define V_ 32000
#define NBLK_REC 64

typedef unsigned short u16;
typedef __attribute__((ext_vector_type(8))) short short8;
typedef __attribute__((ext_vector_type(4))) float f32x4;

static __device__ __forceinline__ u16 f2bf(float f) {
    uint32_t u = __float_as_uint(f);
    uint32_t r = (u + 0x7FFFu + ((u >> 16) & 1u)) >> 16;
    return (u16)r;
}

static __device__ __forceinline__ float sigmf(float x) {
    return 1.0f / (1.0f + __expf(-x));
}

static __device__ __forceinline__ float tanh_f(float x) {
    x = fminf(fmaxf(x, -20.f), 20.f);
    float e = __expf(2.f * x);
    return (e - 1.f) / (e + 1.f);
}

// Direct global->LDS 16B copy (dest is wave-uniform base + lane*16 in HW).
static __device__ __forceinline__ void gload16(const void* g, void* l) {
    __builtin_amdgcn_global_load_lds(
        (const __attribute__((address_space(1))) uint32_t*)g,
        (__attribute__((address_space(3))) uint32_t*)(uint32_t)(uintptr_t)l,
        16, 0, 0);
}

// ---------------------------------------------------------------------------
// Prep: W_comb = W_ih[:,1:] + W_hh  (bf16), wx = W_ih[:,0], biasc = b_ih+b_hh
// Also zeroes the 512 producer sub-flags (re-zeroed every launch/replay).
// ---------------------------------------------------------------------------
__global__ void prep_w(const float* __restrict__ Wih, const float* __restrict__ Whh,
                       const float* __restrict__ bih, const float* __restrict__ bhh,
                       u16* __restrict__ Wc, float* __restrict__ wx, float* __restrict__ biasc,
                       unsigned* __restrict__ flags) {
    int idx = blockIdx.x * 256 + threadIdx.x;      // 4096*1024 threads
    int r = idx >> 10, k = idx & 1023;
    float v = Wih[r * (H_ + 1) + 1 + k] + Whh[idx];
    Wc[idx] = f2bf(v);
    if (k == 0) {
        wx[r] = Wih[r * (H_ + 1)];
        biasc[r] = bih[r] + bhh[r];
    }
    if (idx < 512) flags[idx] = 0u;
}

// W_out fp32 -> bf16 (separate kernel: keeps its 196MB stream OFF the
// recurrence's latency-critical path — r7 fusion cost ~87us of contention).
__global__ void prep_wout(const float* __restrict__ Wout, u16* __restrict__ Wo) {
    long long i = (long long)(blockIdx.x) * 256 + threadIdx.x;   // x4 elements each
    f32x4 v = *(const f32x4*)(Wout + i * 4);
    uint2 o;
    o.x = (uint32_t)f2bf(v[0]) | ((uint32_t)f2bf(v[1]) << 16);
    o.y = (uint32_t)f2bf(v[2]) | ((uint32_t)f2bf(v[3]) << 16);
    *(uint2*)(Wo + i * 4) = o;
}

// ---------------------------------------------------------------------------
// Init: h0 = enc @ W_h^T (bf16), c0 = enc @ W_c^T (fp32).
// ---------------------------------------------------------------------------
__global__ void init_hc(const float* __restrict__ enc, const float* __restrict__ Wh,
                        const float* __restrict__ Wcp, u16* __restrict__ h0,
                        float* __restrict__ c0) {
    int gwid = blockIdx.x * 4 + (threadIdx.x >> 6);   // 2048 waves
    int lane = threadIdx.x & 63;
    int sel = gwid >> 10;                // 0: h, 1: c
    int j = gwid & 1023;
    const float* W = sel ? Wcp : Wh;
    const float* wrow = W + (size_t)j * H_;
    f32x4 wv[4];
#pragma unroll
    for (int it = 0; it < 4; ++it)
        wv[it] = *(const f32x4*)(wrow + it * 256 + lane * 4);
#pragma unroll 2
    for (int b = 0; b < B_; ++b) {
        const float* erow = enc + (size_t)b * H_;
        float acc = 0.f;
#pragma unroll
        for (int it = 0; it < 4; ++it) {
            f32x4 ev = *(const f32x4*)(erow + it * 256 + lane * 4);
            acc += wv[it][0] * ev[0] + wv[it][1] * ev[1] + wv[it][2] * ev[2] + wv[it][3] * ev[3];
        }
#pragma unroll
        for (int s = 32; s >= 1; s >>= 1) acc += __shfl_xor(acc, s, 64);
        if (lane == 0) {
            if (sel) c0[(size_t)b * H_ + j] = acc;
            else     h0[(size_t)b * H_ + j] = f2bf(acc);
        }
    }
}

// ---------------------------------------------------------------------------
// Persistent LSTM recurrence (r7 protocol, un-fused). 64 blocks x 512 threads.
// ---------------------------------------------------------------------------
__global__ __launch_bounds__(512, 1) void lstm_persist(
    const u16* __restrict__ Wc, const float* __restrict__ wx,
    const float* __restrict__ biasc, const u16* __restrict__ h0,
    const float* __restrict__ c0, const float* __restrict__ y,
    u16* __restrict__ A, unsigned* __restrict__ flags) {
    __shared__ float red[8][64 * 33];    // 8 K-wave partials, padded
    __shared__ float cs[16][33];         // cell state [jlx][b], padded
    __shared__ float wxs[64], bcs[64];   // per-row x-weight / bias
    __shared__ float ys[32 * 129];       // y staged, padded stride 129

    int tid = threadIdx.x;
    int lane = tid & 63;
    int w = tid >> 6;                    // wave id 0..7: K-slice w*128 AND j-cols 2w,2w+1
    int bid = blockIdx.x;
    int j0 = bid * 16;
    int jl = lane & 15;                  // MFMA A-row / B-col lane index
    int kc = (lane >> 4) * 8;            // k-offset within 32-chunk
    int delta = lane >> 5, b = lane & 31;
    int jlx = 2 * w + delta;             // this thread's j column (pointwise)

    // ---- one-time: weights to registers (resident), pinned ----
    short8 afr[4][4];
    {
        const u16* abase = Wc + (size_t)(j0 + jl) * H_ + w * 128 + kc;
#pragma unroll
        for (int g = 0; g < 4; ++g)
#pragma unroll
            for (int ks = 0; ks < 4; ++ks)
                afr[g][ks] = *(const short8*)(abase + (size_t)g * H_ * H_ + ks * 32);
    }
#pragma unroll
    for (int g = 0; g < 4; ++g)
#pragma unroll
        for (int ks = 0; ks < 4; ++ks)
            asm volatile("" : "+v"(afr[g][ks]));   // pin: defeat remat/reload

    if (tid < 64) {
        int g = tid >> 4, q = tid & 15;
        wxs[tid] = wx[(size_t)g * H_ + j0 + q];
        bcs[tid] = biasc[(size_t)g * H_ + j0 + q];
    }
#pragma unroll
    for (int i = tid; i < B_ * T_; i += 512)
        ys[(i >> 7) * 129 + (i & 127)] = y[i];
    cs[jlx][b] = c0[(size_t)b * H_ + j0 + jlx];
    __syncthreads();

    for (int t = 0; t < T_; ++t) {
        const u16* hp = (t == 0) ? h0 : (A + (size_t)(t - 1) * B_ * H_);

        // ---- per-wave slice wait: 64 sub-flags of blocks 8w..8w+7 ----
        if (t > 0) {
            const unsigned* fp = &flags[(w << 6) + lane];
            unsigned target = (unsigned)t;
            int guard = 0;
            for (;;) {
                unsigned v = __hip_atomic_load(fp, __ATOMIC_RELAXED, __HIP_MEMORY_SCOPE_AGENT);
                if (__all(v >= target)) break;
                if (++guard > 20000000) break;   // hang-safety; never triggers co-resident
            }
            __atomic_signal_fence(__ATOMIC_ACQUIRE);
        }

        // ---- load h b-frags for this wave's k-slice and MFMA ----
        short8 bfr0[4], bfr1[4];
        {
            const u16* hb = hp + (size_t)jl * H_ + w * 128 + kc;
#pragma unroll
            for (int ks = 0; ks < 4; ++ks) {
                bfr0[ks] = *(const short8*)(hb + ks * 32);
                bfr1[ks] = *(const short8*)(hb + (size_t)16 * H_ + ks * 32);
            }
        }
        f32x4 acc[4][2] = {};
#pragma unroll
        for (int ks = 0; ks < 4; ++ks) {
#pragma unroll
            for (int g = 0; g < 4; ++g) {
                acc[g][0] = __builtin_amdgcn_mfma_f32_16x16x32_bf16(afr[g][ks], bfr0[ks], acc[g][0], 0, 0, 0);
                acc[g][1] = __builtin_amdgcn_mfma_f32_16x16x32_bf16(afr[g][ks], bfr1[ks], acc[g][1], 0, 0, 0);
            }
        }
        int r0 = (lane >> 4) * 4;
#pragma unroll
        for (int g = 0; g < 4; ++g)
#pragma unroll
            for (int bt = 0; bt < 2; ++bt)
#pragma unroll
                for (int r = 0; r < 4; ++r)
                    red[w][(g * 16 + r0 + r) * 33 + bt * 16 + jl] = acc[g][bt][r];
        __syncthreads();   // red RAW

        // ---- pointwise for THIS wave's 2 j-columns; store; own drain; flag --
        {
            float yv = ys[b * 129 + t];
            float pg[4];
#pragma unroll
            for (int g = 0; g < 4; ++g) {
                int row = (g * 16 + jlx) * 33 + b;
                float sum = red[0][row];
#pragma unroll
                for (int ww = 1; ww < 8; ++ww) sum += red[ww][row];
                pg[g] = sum + wxs[g * 16 + jlx] * yv + bcs[g * 16 + jlx];
            }
            float iv = sigmf(pg[0]);
            float fv = sigmf(pg[1]);
            float gv = tanh_f(pg[2]);
            float ov = sigmf(pg[3]);
            float cv = fv * cs[jlx][b] + iv * gv;
            cs[jlx][b] = cv;
            float hv = ov * tanh_f(cv);

            unsigned hb16 = (unsigned)f2bf(hv);
            unsigned oth = (unsigned)__shfl((int)hb16, lane + 32, 64); // odd-j partner
            if (delta == 0) {
                uint32_t pk = hb16 | (oth << 16);
                __hip_atomic_store((uint32_t*)(A + ((size_t)t * B_ + b) * H_ + j0 + 2 * w),
                                   pk, __ATOMIC_RELAXED, __HIP_MEMORY_SCOPE_AGENT);
            }
            asm volatile("s_waitcnt vmcnt(0)" ::: "memory");   // own stores visible
            if (lane == 0)
                __hip_atomic_store(&flags[bid * 8 + w], (unsigned)(t + 1),
                                   __ATOMIC_RELAXED, __HIP_MEMORY_SCOPE_AGENT);
        }
        __syncthreads();   // red WAR
    }
}

// ---------------------------------------------------------------------------
// Output GEMM — 256x256 8-phase template (T3+T4+T2+T5), BK=64, 8 waves.
// A layout [t][b][k]; m-tile = 2 batches. LDS 128KB: 2 bufs x 4 halves
// (A0,A1,B0,B1) x 16KB. One half-tile staged per phase (2 gload_lds/thread),
// counted vmcnt(4) once per K-tile, raw s_barrier (no vmcnt-drain),
// XOR swizzle col16^=(row&7): pre-swizzled gload source + swizzled ds_read.
// Wave (wm 0-1, wn 0-3): m rows {wm*64..+64} of each A-half (mt 0-3 half0,
// 4-7 half1), n cols {wn*32..+32} of each B-half. Per phase q: quadrant
// (mh=q>>1, nh=q&1), 12 ds_read_b128 + 16 MFMA.
// ---------------------------------------------------------------------------
__global__ __launch_bounds__(512, 2) void gemm_out(
    const u16* __restrict__ A, const u16* __restrict__ Wo,
    const float* __restrict__ bout, float* __restrict__ out) {
    __shared__ __align__(16) u16 sb[65536];   // 128KB

    int orig = blockIdx.x;                    // 2000 = 8 XCDs * 250
    int w = (orig & 7) * 250 + (orig >> 3);   // bijective XCD chunking
    int mtile = w & 15;                       // 16 m-tiles (2 batches each)
    int n0g = (w >> 4) << 8;                  // 125 n-tiles * 256

    int tid = threadIdx.x, lane = tid & 63, wid = tid >> 6;
    int wm = wid >> 2, wn = wid & 3;
    int jl = lane & 15, kq = lane >> 4;

    f32x4 acc[8][4] = {};

    // stage one half-tile h (0=A0,1=A1,2=B0,3=B1) of K-tile `tile`
    auto stage = [&](int tile, int h) {
        u16* dst = sb + ((tile & 1) << 15) + (h << 13) + tid * 8;
#pragma unroll
        for (int ld = 0; ld < 2; ++ld) {
            int p = tid + (ld << 9);
            int row = p >> 3;
            int c16 = (p & 7) ^ (row & 7);        // inverse-swizzled source
            const u16* src;
            if (h < 2)   // A: batch = mtile*2 + h, t = row
                src = A + ((size_t)row * B_ + (size_t)(mtile * 2 + h)) * H_
                        + tile * 64 + c16 * 8;
            else         // B: n-row
                src = Wo + (size_t)(n0g + ((h - 2) << 7) + row) * H_
                         + tile * 64 + c16 * 8;
            gload16(src, dst + (ld << 12));
        }
    };

    // ---- prologue: tile0 fully + A0,B0 of tile1; allow those 4 pending ----
    stage(0, 0); stage(0, 2); stage(0, 1); stage(0, 3);
    stage(1, 0); stage(1, 2);
    asm volatile("s_waitcnt vmcnt(4)" ::: "memory");
    __builtin_amdgcn_s_barrier();

    const int NT = 16;   // K/64
    for (int tile = 0; tile < NT; ++tile) {
        const u16* buf = sb + ((tile & 1) << 15);
#pragma unroll
        for (int q = 0; q < 4; ++q) {
            const int mh = q >> 1, nh = q & 1;
            short8 af[4][2], bf[2][2];
            const u16* bufA = buf + (mh << 13);
            const u16* bufB = buf + (1 << 14) + (nh << 13);
#pragma unroll
            for (int i = 0; i < 4; ++i) {
                int row = wm * 64 + (i << 4) + jl;
                int rx = (row & 7) << 3;
#pragma unroll
                for (int k2 = 0; k2 < 2; ++k2)
                    af[i][k2] = *(const short8*)(bufA + row * 64 + (((k2 << 5) + (kq << 3)) ^ rx));
            }
#pragma unroll
            for (int i = 0; i < 2; ++i) {
                int row = wn * 32 + (i << 4) + jl;
                int rx = (row & 7) << 3;
#pragma unroll
                for (int k2 = 0; k2 < 2; ++k2)
                    bf[i][k2] = *(const short8*)(bufB + row * 64 + (((k2 << 5) + (kq << 3)) ^ rx));
            }
            // stage schedule: q0:A1(t+1) q1:B1(t+1) q2:A0(t+2) q3:B0(t+2)
            if (q == 0) { if (tile + 1 < NT) stage(tile + 1, 1); }
            if (q == 1) { if (tile + 1 < NT) stage(tile + 1, 3); }
            if (q == 2) { if (tile + 2 < NT) stage(tile + 2, 0); }
            if (q == 3) { if (tile + 2 < NT) stage(tile + 2, 2); }

            asm volatile("" ::: "memory");
            __builtin_amdgcn_s_barrier();
            asm volatile("" ::: "memory");
            __builtin_amdgcn_s_setprio(1);
#pragma unroll
            for (int i = 0; i < 4; ++i)
#pragma unroll
                for (int jn = 0; jn < 2; ++jn)
#pragma unroll
                    for (int k2 = 0; k2 < 2; ++k2)
                        acc[mh * 4 + i][nh * 2 + jn] =
                            __builtin_amdgcn_mfma_f32_16x16x32_bf16(
                                af[i][k2], bf[jn][k2], acc[mh * 4 + i][nh * 2 + jn], 0, 0, 0);
            __builtin_amdgcn_s_setprio(0);
            // tile boundary: verify next tile's halves landed (counted, not 0)
            if (q == 3) {
                if (tile < 13) asm volatile("s_waitcnt vmcnt(4)" ::: "memory");
                else           asm volatile("s_waitcnt vmcnt(0)" ::: "memory");
            }
            asm volatile("" ::: "memory");
            __builtin_amdgcn_s_barrier();
        }
    }

    // ---- epilogue: per-wave private LDS transpose, bias, t-major stores ----
    __syncthreads();
    float* tr = (float*)sb;
    float* wsl = tr + wid * 2112;     // 16 rows x stride 132 per wave
    int b0 = mtile * 2;
#pragma unroll
    for (int nt = 0; nt < 4; ++nt) {
        {
            int n = n0g + ((nt >> 1) << 7) + wn * 32 + ((nt & 1) << 4) + jl;
            float bias = bout[n];
#pragma unroll
            for (int mt = 0; mt < 8; ++mt) {
                f32x4 v = acc[mt][nt];
                v[0] += bias; v[1] += bias; v[2] += bias; v[3] += bias;
                *(f32x4*)(wsl + jl * 132 + mt * 16 + kq * 4) = v;   // [n_loc][m_loc]
            }
        }
        // read own wave's slice (lgkm auto-ordered), store 128B/lane
        {
            int row = lane >> 2;                  // n_loc 0..15
            int seg = lane & 3;                   // m_loc segment of 32
            int n = n0g + ((nt >> 1) << 7) + wn * 32 + ((nt & 1) << 4) + row;
            int bb = b0 + (seg >> 1);
            int t0 = wm * 64 + ((seg & 1) << 5);
            const float* sp = wsl + row * 132 + (seg << 5);
            float* dst = out + ((size_t)bb * V_ + n) * T_ + t0;
#pragma unroll
            for (int k = 0; k < 8; ++k)
                *(f32x4*)(dst + (k << 2)) = *(const f32x4*)(sp + (k << 2));
        }
    }
}

// ---------------------------------------------------------------------------
extern "C" void kernel_launch(void* const* d_in, const int* in_sizes, int n_in,
                              void* d_out, int out_size, void* d_ws, size_t ws_size,
                              hipStream_t stream) {
    const float* y    = (const float*)d_in[0];   // [B,T]
    const float* enc  = (const float*)d_in[1];   // [B,H]
    const float* Wh   = (const float*)d_in[2];   // [H,H]
    const float* Wcp  = (const float*)d_in[3];   // [H,H]
    const float* Wih  = (const float*)d_in[4];   // [4H,1+H]
    const float* Whh  = (const float*)d_in[5];   // [4H,H]
    const float* bih  = (const float*)d_in[6];   // [4H]
    const float* bhh  = (const float*)d_in[7];   // [4H]
    const float* Wout = (const float*)d_in[8];   // [V,H]
    const float* bout = (const float*)d_in[9];   // [V]

    uint8_t* ws = (uint8_t*)d_ws;
    u16*  Wcomb = (u16*)ws;                                   // 8,388,608 B
    u16*  Wo    = (u16*)(ws + 8388608);                       // 65,536,000 B
    float* wx    = (float*)(ws + 8388608 + 65536000);
    float* biasc = wx + 4096;
    u16*  h0    = (u16*)(biasc + 4096);
    float* c     = (float*)(h0 + 32 * 1024);
    u16*  A     = (u16*)(c + 32 * 1024);                      // [T][B][H] bf16
    unsigned* flags = (unsigned*)(A + (size_t)4096 * 1024);   // 512*4 B

    prep_w<<<16384, 256, 0, stream>>>(Wih, Whh, bih, bhh, Wcomb, wx, biasc, flags);
    prep_wout<<<32000, 256, 0, stream>>>(Wout, Wo);
    init_hc<<<512, 256, 0, stream>>>(enc, Wh, Wcp, h0, c);

    lstm_persist<<<NBLK_REC, 512, 0, stream>>>(Wcomb, wx, biasc, h0, c, y, A, flags);

    gemm_out<<<2000, 512, 0, stream>>>(A, Wo, bout, (float*)d_out);
}

// Round 9
// 933.251 us; speedup vs baseline: 1.3030x; 1.2924x over previous
//
#include <hip/hip_runtime.h>
#include <hip/hip_bf16.h>
#include <stdint.h>

#define B_ 32
#define T_ 128
#define H_ 1024
#define V_ 32000
#define NBLK_REC 64

typedef unsigned short u16;
typedef __attribute__((ext_vector_type(8))) short short8;
typedef __attribute__((ext_vector_type(4))) float f32x4;

static __device__ __forceinline__ u16 f2bf(float f) {
    uint32_t u = __float_as_uint(f);
    uint32_t r = (u + 0x7FFFu + ((u >> 16) & 1u)) >> 16;
    return (u16)r;
}

static __device__ __forceinline__ float sigmf(float x) {
    return 1.0f / (1.0f + __expf(-x));
}

static __device__ __forceinline__ float tanh_f(float x) {
    x = fminf(fmaxf(x, -20.f), 20.f);
    float e = __expf(2.f * x);
    return (e - 1.f) / (e + 1.f);
}

// Direct global->LDS 16B copy (dest is wave-uniform base + lane*16 in HW).
static __device__ __forceinline__ void gload16(const void* g, void* l) {
    __builtin_amdgcn_global_load_lds(
        (const __attribute__((address_space(1))) uint32_t*)g,
        (__attribute__((address_space(3))) uint32_t*)(uint32_t)(uintptr_t)l,
        16, 0, 0);
}

// ---------------------------------------------------------------------------
// Prep: W_comb = W_ih[:,1:] + W_hh  (bf16), wx = W_ih[:,0], biasc = b_ih+b_hh
// Also zeroes the 64 producer flags (re-zeroed every launch/replay).
// ---------------------------------------------------------------------------
__global__ void prep_w(const float* __restrict__ Wih, const float* __restrict__ Whh,
                       const float* __restrict__ bih, const float* __restrict__ bhh,
                       u16* __restrict__ Wc, float* __restrict__ wx, float* __restrict__ biasc,
                       unsigned* __restrict__ flags) {
    int idx = blockIdx.x * 256 + threadIdx.x;      // 4096*1024 threads
    int r = idx >> 10, k = idx & 1023;
    float v = Wih[r * (H_ + 1) + 1 + k] + Whh[idx];
    Wc[idx] = f2bf(v);
    if (k == 0) {
        wx[r] = Wih[r * (H_ + 1)];
        biasc[r] = bih[r] + bhh[r];
    }
    if (idx < 512) flags[idx] = 0u;
}

// W_out fp32 -> bf16 (separate: its 196MB stream stays off the latency path).
__global__ void prep_wout(const float* __restrict__ Wout, u16* __restrict__ Wo) {
    long long i = (long long)(blockIdx.x) * 256 + threadIdx.x;   // x4 elements each
    f32x4 v = *(const f32x4*)(Wout + i * 4);
    uint2 o;
    o.x = (uint32_t)f2bf(v[0]) | ((uint32_t)f2bf(v[1]) << 16);
    o.y = (uint32_t)f2bf(v[2]) | ((uint32_t)f2bf(v[3]) << 16);
    *(uint2*)(Wo + i * 4) = o;
}

// ---------------------------------------------------------------------------
// Init: h0 = enc @ W_h^T (bf16), c0 = enc @ W_c^T (fp32).
// ---------------------------------------------------------------------------
__global__ void init_hc(const float* __restrict__ enc, const float* __restrict__ Wh,
                        const float* __restrict__ Wcp, u16* __restrict__ h0,
                        float* __restrict__ c0) {
    int gwid = blockIdx.x * 4 + (threadIdx.x >> 6);   // 2048 waves
    int lane = threadIdx.x & 63;
    int sel = gwid >> 10;                // 0: h, 1: c
    int j = gwid & 1023;
    const float* W = sel ? Wcp : Wh;
    const float* wrow = W + (size_t)j * H_;
    f32x4 wv[4];
#pragma unroll
    for (int it = 0; it < 4; ++it)
        wv[it] = *(const f32x4*)(wrow + it * 256 + lane * 4);
#pragma unroll 2
    for (int b = 0; b < B_; ++b) {
        const float* erow = enc + (size_t)b * H_;
        float acc = 0.f;
#pragma unroll
        for (int it = 0; it < 4; ++it) {
            f32x4 ev = *(const f32x4*)(erow + it * 256 + lane * 4);
            acc += wv[it][0] * ev[0] + wv[it][1] * ev[1] + wv[it][2] * ev[2] + wv[it][3] * ev[3];
        }
#pragma unroll
        for (int s = 32; s >= 1; s >>= 1) acc += __shfl_xor(acc, s, 64);
        if (lane == 0) {
            if (sel) c0[(size_t)b * H_ + j] = acc;
            else     h0[(size_t)b * H_ + j] = f2bf(acc);
        }
    }
}

// ---------------------------------------------------------------------------
// FUSED kernel: blocks 0..63 = persistent LSTM recurrence (r6 protocol);
// blocks 64..2063 = gated output GEMM (256x256 8-phase, m-tile = 32t x 8b).
// Gemm block for t-block tb waits until flags[all 64 producers] >= (tb+1)*32,
// so gemm overlaps the recurrence on the 192 otherwise-idle CUs.
// Dispatch order: recurrence first (co-residency), then gemm tb-ascending.
// ---------------------------------------------------------------------------
__global__ __launch_bounds__(512, 2) void fused_all(
    const u16* __restrict__ Wc, const float* __restrict__ wx,
    const float* __restrict__ biasc, const u16* __restrict__ h0,
    const float* __restrict__ c0, const float* __restrict__ y,
    u16* __restrict__ A, unsigned* __restrict__ flags,
    const u16* __restrict__ Wo, const float* __restrict__ bout,
    float* __restrict__ out) {
    __shared__ __align__(16) u16 sb[65536];   // 128KB pool (both roles)

    int tid = threadIdx.x;
    int lane = tid & 63;

    if (blockIdx.x < NBLK_REC) {
        // ================= recurrence (r6 protocol, 653us proven) =========
        float* red = (float*)sb;             // [8][64*33] = 16896 f
        float* cs  = red + 8 * 2112;         // [16][33]
        float* wxs = cs + 16 * 33;           // [64]
        float* bcs = wxs + 64;               // [64]
        float* ys  = bcs + 64;               // [32][129]

        int kw = tid >> 6;                   // wave id = K-slice
        int bid = blockIdx.x;
        int j0 = bid * 16;
        int jl = lane & 15;
        int kc = (lane >> 4) * 8;
        int jj = tid & 7, pb = tid >> 3;     // pointwise mapping (tid<256)

        short8 afr[4][4];
        {
            const u16* abase = Wc + (size_t)(j0 + jl) * H_ + kw * 128 + kc;
#pragma unroll
            for (int g = 0; g < 4; ++g)
#pragma unroll
                for (int ks = 0; ks < 4; ++ks)
                    afr[g][ks] = *(const short8*)(abase + (size_t)g * H_ * H_ + ks * 32);
        }
#pragma unroll
        for (int g = 0; g < 4; ++g)
#pragma unroll
            for (int ks = 0; ks < 4; ++ks)
                asm volatile("" : "+v"(afr[g][ks]));   // pin: defeat remat

        if (tid < 64) {
            int g = tid >> 4, qq = tid & 15;
            wxs[tid] = wx[(size_t)g * H_ + j0 + qq];
            bcs[tid] = biasc[(size_t)g * H_ + j0 + qq];
        }
#pragma unroll
        for (int i = tid; i < B_ * T_; i += 512)
            ys[(i >> 7) * 129 + (i & 127)] = y[i];
        if (tid < 256) {
            cs[(2 * jj) * 33 + pb]     = c0[(size_t)pb * H_ + j0 + 2 * jj];
            cs[(2 * jj + 1) * 33 + pb] = c0[(size_t)pb * H_ + j0 + 2 * jj + 1];
        }
        __syncthreads();

        for (int t = 0; t < T_; ++t) {
            const u16* hp = (t == 0) ? h0 : (A + (size_t)(t - 1) * B_ * H_);

            if (t > 0) {
                const unsigned* fp = &flags[kw * 8 + (lane & 7)];
                unsigned target = (unsigned)t;
                int guard = 0;
                for (;;) {
                    unsigned v = __hip_atomic_load(fp, __ATOMIC_RELAXED, __HIP_MEMORY_SCOPE_AGENT);
                    if (__all(v >= target)) break;
                    if (++guard > 20000000) break;
                }
                __atomic_signal_fence(__ATOMIC_ACQUIRE);
            }

            short8 bf0[4], bf1[4];
            {
                const u16* hb = hp + (size_t)jl * H_ + kw * 128 + kc;
#pragma unroll
                for (int ks = 0; ks < 4; ++ks) {
                    bf0[ks] = *(const short8*)(hb + ks * 32);
                    bf1[ks] = *(const short8*)(hb + (size_t)16 * H_ + ks * 32);
                }
            }
            f32x4 acc[4][2] = {};
#pragma unroll
            for (int ks = 0; ks < 4; ++ks) {
#pragma unroll
                for (int g = 0; g < 4; ++g) {
                    acc[g][0] = __builtin_amdgcn_mfma_f32_16x16x32_bf16(afr[g][ks], bf0[ks], acc[g][0], 0, 0, 0);
                    acc[g][1] = __builtin_amdgcn_mfma_f32_16x16x32_bf16(afr[g][ks], bf1[ks], acc[g][1], 0, 0, 0);
                }
            }
            int r0 = (lane >> 4) * 4;
#pragma unroll
            for (int g = 0; g < 4; ++g)
#pragma unroll
                for (int bt = 0; bt < 2; ++bt)
#pragma unroll
                    for (int r = 0; r < 4; ++r)
                        red[kw * 2112 + (g * 16 + r0 + r) * 33 + bt * 16 + jl] = acc[g][bt][r];
            __syncthreads();   // red RAW

            if (tid < 256) {
                float yv = ys[pb * 129 + t];
                float hv[2];
#pragma unroll
                for (int s = 0; s < 2; ++s) {
                    int jlx = 2 * jj + s;
                    float pg[4];
#pragma unroll
                    for (int g = 0; g < 4; ++g) {
                        int row = (g * 16 + jlx) * 33 + pb;
                        float sum = red[row];
#pragma unroll
                        for (int ww = 1; ww < 8; ++ww) sum += red[ww * 2112 + row];
                        pg[g] = sum + wxs[g * 16 + jlx] * yv + bcs[g * 16 + jlx];
                    }
                    float iv = sigmf(pg[0]);
                    float fv = sigmf(pg[1]);
                    float gv = tanh_f(pg[2]);
                    float ov = sigmf(pg[3]);
                    float cv = fv * cs[jlx * 33 + pb] + iv * gv;
                    cs[jlx * 33 + pb] = cv;
                    hv[s] = ov * tanh_f(cv);
                }
                uint32_t pk = (uint32_t)f2bf(hv[0]) | ((uint32_t)f2bf(hv[1]) << 16);
                __hip_atomic_store((uint32_t*)(A + ((size_t)t * B_ + pb) * H_ + j0 + 2 * jj),
                                   pk, __ATOMIC_RELAXED, __HIP_MEMORY_SCOPE_AGENT);
            }
            // Barrier drains every thread's vmcnt -> h_t stores visible.
            __syncthreads();
            if (tid == 0)
                __hip_atomic_store(&flags[bid], (unsigned)(t + 1),
                                   __ATOMIC_RELAXED, __HIP_MEMORY_SCOPE_AGENT);
        }
        return;
    }

    // ================= gated output GEMM ==================================
    // m-tile = 32 t x 8 b (b-major rows): global m-row R (0..255):
    //   b = bb*8 + (R>>5), t = tb*32 + (R&31). Half h holds R in [h*128,+128).
    int orig = blockIdx.x - NBLK_REC;         // 0..1999
    int tb = orig / 500;                      // gate group, dispatch-ascending
    int wp = orig - tb * 500;
    int xcd = wp & 7, rest = wp >> 3;         // m204 bijective swizzle (500=8*62+4)
    int wg = (xcd < 4 ? xcd * 63 : 252 + (xcd - 4) * 62) + rest;
    int bb = wg / 125;                        // 0..3
    int nb = wg - bb * 125;                   // 0..124
    int n0g = nb << 8;

    int wid = tid >> 6;
    int wm = wid >> 2, wn = wid & 3;
    int jl = lane & 15, kq = lane >> 4;

    f32x4 acc[8][4] = {};

    // stage half-tile h (0=A0,1=A1,2=B0,3=B1) of K-tile `tile`
    auto stage = [&](int tile, int h) {
        u16* dst = sb + ((tile & 1) << 15) + (h << 13) + tid * 8;
#pragma unroll
        for (int ld = 0; ld < 2; ++ld) {
            int p = tid + (ld << 9);
            int row = p >> 3;
            int c16 = (p & 7) ^ (row & 7);        // inverse-swizzled source
            const u16* src;
            if (h < 2)
                src = A + ((size_t)(tb * 32 + (row & 31)) * B_
                           + (size_t)(bb * 8 + h * 4 + (row >> 5))) * H_
                        + tile * 64 + c16 * 8;
            else
                src = Wo + (size_t)(n0g + ((h - 2) << 7) + row) * H_
                         + tile * 64 + c16 * 8;
            gload16(src, dst + (ld << 12));
        }
    };

    // pre-gate: warm the B panels of tile 0 (Wo ready from prep_wout)
    stage(0, 2); stage(0, 3);

    // ---- gate: wave 0 polls all 64 producer flags; others park ----
    if (wid == 0) {
        unsigned target = (unsigned)((tb + 1) * 32);
        const unsigned* fp = &flags[lane];
        int guard = 0;
        for (;;) {
            unsigned v = __hip_atomic_load(fp, __ATOMIC_RELAXED, __HIP_MEMORY_SCOPE_AGENT);
            if (__all(v >= target)) break;
            __builtin_amdgcn_s_sleep(16);
            if (++guard > 20000000) break;   // hang-safety
        }
        __atomic_signal_fence(__ATOMIC_ACQUIRE);
    }
    __builtin_amdgcn_s_barrier();

    // ---- prologue: A of tile0 + A0,B0 of tile1; leave 4 in flight ----
    stage(0, 0); stage(0, 1); stage(1, 0); stage(1, 2);
    asm volatile("s_waitcnt vmcnt(4)" ::: "memory");
    __builtin_amdgcn_s_barrier();

    const int NT = 16;   // K/64
    for (int tile = 0; tile < NT; ++tile) {
        const u16* buf = sb + ((tile & 1) << 15);
#pragma unroll
        for (int q = 0; q < 4; ++q) {
            const int mh = q >> 1, nh = q & 1;
            short8 af[4][2], bfr[2][2];
            const u16* bufA = buf + (mh << 13);
            const u16* bufB = buf + (1 << 14) + (nh << 13);
#pragma unroll
            for (int i = 0; i < 4; ++i) {
                int row = wm * 64 + (i << 4) + jl;
                int rx = (row & 7) << 3;
#pragma unroll
                for (int k2 = 0; k2 < 2; ++k2)
                    af[i][k2] = *(const short8*)(bufA + row * 64 + (((k2 << 5) + (kq << 3)) ^ rx));
            }
#pragma unroll
            for (int i = 0; i < 2; ++i) {
                int row = wn * 32 + (i << 4) + jl;
                int rx = (row & 7) << 3;
#pragma unroll
                for (int k2 = 0; k2 < 2; ++k2)
                    bfr[i][k2] = *(const short8*)(bufB + row * 64 + (((k2 << 5) + (kq << 3)) ^ rx));
            }
            if (q == 0) { if (tile + 1 < NT) stage(tile + 1, 1); }
            if (q == 1) { if (tile + 1 < NT) stage(tile + 1, 3); }
            if (q == 2) { if (tile + 2 < NT) stage(tile + 2, 0); }
            if (q == 3) { if (tile + 2 < NT) stage(tile + 2, 2); }

            asm volatile("" ::: "memory");
            __builtin_amdgcn_s_barrier();
            asm volatile("" ::: "memory");
            __builtin_amdgcn_s_setprio(1);
#pragma unroll
            for (int i = 0; i < 4; ++i)
#pragma unroll
                for (int jn = 0; jn < 2; ++jn)
#pragma unroll
                    for (int k2 = 0; k2 < 2; ++k2)
                        acc[mh * 4 + i][nh * 2 + jn] =
                            __builtin_amdgcn_mfma_f32_16x16x32_bf16(
                                af[i][k2], bfr[jn][k2], acc[mh * 4 + i][nh * 2 + jn], 0, 0, 0);
            __builtin_amdgcn_s_setprio(0);
            if (q == 3) {
                if (tile < 14) asm volatile("s_waitcnt vmcnt(4)" ::: "memory");
                else           asm volatile("s_waitcnt vmcnt(0)" ::: "memory");
            }
            asm volatile("" ::: "memory");
            __builtin_amdgcn_s_barrier();
        }
    }

    // ---- epilogue: per-wave LDS transpose to [n][b][t], 64B t-runs ----
    __syncthreads();
    float* wsl = (float*)sb + wid * 2048;     // 16n x 4b x 32t per wave
#pragma unroll
    for (int nt = 0; nt < 4; ++nt) {
        {
            int n = n0g + ((nt >> 1) << 7) + wn * 32 + ((nt & 1) << 4) + jl;
            float bias = bout[n];
#pragma unroll
            for (int mt = 0; mt < 8; ++mt) {
                int mh = mt >> 2, i = mt & 3;
                int b2 = mh * 2 + (i >> 1);
                int g = ((i & 1) << 2) + kq;       // t-group 0..7
                f32x4 v = acc[mt][nt];
                v[0] += bias; v[1] += bias; v[2] += bias; v[3] += bias;
                *(f32x4*)(wsl + jl * 128 + b2 * 32 + ((g ^ (jl & 7)) << 2)) = v;
            }
        }
#pragma unroll
        for (int rr = 0; rr < 2; ++rr) {
            int flat = lane * 2 + rr;              // 0..127
            int jr = flat >> 3;                    // n_loc 0..15
            int b2r = (flat >> 1) & 3;
            int h2 = flat & 1;                     // t half (0..15 / 16..31)
            int n2 = n0g + ((nt >> 1) << 7) + wn * 32 + ((nt & 1) << 4) + jr;
            int bo = bb * 8 + (b2r >> 1) * 4 + wm * 2 + (b2r & 1);
            int t0 = tb * 32 + h2 * 16;
            float* dst = out + ((size_t)bo * V_ + n2) * T_ + t0;
            const float* sp = wsl + jr * 128 + b2r * 32;
#pragma unroll
            for (int gg = 0; gg < 4; ++gg) {
                int g2 = h2 * 4 + gg;
                f32x4 v = *(const f32x4*)(sp + ((g2 ^ (jr & 7)) << 2));
                *(f32x4*)(dst + (gg << 2)) = v;
            }
        }
    }
}

// ---------------------------------------------------------------------------
extern "C" void kernel_launch(void* const* d_in, const int* in_sizes, int n_in,
                              void* d_out, int out_size, void* d_ws, size_t ws_size,
                              hipStream_t stream) {
    const float* y    = (const float*)d_in[0];   // [B,T]
    const float* enc  = (const float*)d_in[1];   // [B,H]
    const float* Wh   = (const float*)d_in[2];   // [H,H]
    const float* Wcp  = (const float*)d_in[3];   // [H,H]
    const float* Wih  = (const float*)d_in[4];   // [4H,1+H]
    const float* Whh  = (const float*)d_in[5];   // [4H,H]
    const float* bih  = (const float*)d_in[6];   // [4H]
    const float* bhh  = (const float*)d_in[7];   // [4H]
    const float* Wout = (const float*)d_in[8];   // [V,H]
    const float* bout = (const float*)d_in[9];   // [V]

    uint8_t* ws = (uint8_t*)d_ws;
    u16*  Wcomb = (u16*)ws;                                   // 8,388,608 B
    u16*  Wo    = (u16*)(ws + 8388608);                       // 65,536,000 B
    float* wx    = (float*)(ws + 8388608 + 65536000);
    float* biasc = wx + 4096;
    u16*  h0    = (u16*)(biasc + 4096);
    float* c     = (float*)(h0 + 32 * 1024);
    u16*  A     = (u16*)(c + 32 * 1024);                      // [T][B][H] bf16
    unsigned* flags = (unsigned*)(A + (size_t)4096 * 1024);   // 512*4 B

    prep_w<<<16384, 256, 0, stream>>>(Wih, Whh, bih, bhh, Wcomb, wx, biasc, flags);
    prep_wout<<<32000, 256, 0, stream>>>(Wout, Wo);
    init_hc<<<512, 256, 0, stream>>>(enc, Wh, Wcp, h0, c);

    fused_all<<<NBLK_REC + 2000, 512, 0, stream>>>(
        Wcomb, wx, biasc, h0, c, y, A, flags, Wo, bout, (float*)d_out);
}

// Round 10
// 740.641 us; speedup vs baseline: 1.6418x; 1.2601x over previous
//
#include <hip/hip_runtime.h>
#include <hip/hip_bf16.h>
#include <stdint.h>

#define B_ 32
#define T_ 128
#define H_ 1024
#define V_ 32000
#define NBLK_REC 64

typedef unsigned short u16;
typedef __attribute__((ext_vector_type(8))) short short8;
typedef __attribute__((ext_vector_type(4))) float f32x4;

static __device__ __forceinline__ u16 f2bf(float f) {
    uint32_t u = __float_as_uint(f);
    uint32_t r = (u + 0x7FFFu + ((u >> 16) & 1u)) >> 16;
    return (u16)r;
}

static __device__ __forceinline__ float sigmf(float x) {
    return 1.0f / (1.0f + __expf(-x));
}

static __device__ __forceinline__ float tanh_f(float x) {
    x = fminf(fmaxf(x, -20.f), 20.f);
    float e = __expf(2.f * x);
    return (e - 1.f) / (e + 1.f);
}

// Direct global->LDS 16B copy (dest is wave-uniform base + lane*16 in HW).
static __device__ __forceinline__ void gload16(const void* g, void* l) {
    __builtin_amdgcn_global_load_lds(
        (const __attribute__((address_space(1))) uint32_t*)g,
        (__attribute__((address_space(3))) uint32_t*)(uint32_t)(uintptr_t)l,
        16, 0, 0);
}

// ---------------------------------------------------------------------------
// Prep: W_comb = W_ih[:,1:] + W_hh  (bf16), wx = W_ih[:,0], biasc = b_ih+b_hh
// Also zeroes the line-spread producer flags (64 x 32 ints = 8KB).
// ---------------------------------------------------------------------------
__global__ void prep_w(const float* __restrict__ Wih, const float* __restrict__ Whh,
                       const float* __restrict__ bih, const float* __restrict__ bhh,
                       u16* __restrict__ Wc, float* __restrict__ wx, float* __restrict__ biasc,
                       unsigned* __restrict__ flags) {
    int idx = blockIdx.x * 256 + threadIdx.x;      // 4096*1024 threads
    int r = idx >> 10, k = idx & 1023;
    float v = Wih[r * (H_ + 1) + 1 + k] + Whh[idx];
    Wc[idx] = f2bf(v);
    if (k == 0) {
        wx[r] = Wih[r * (H_ + 1)];
        biasc[r] = bih[r] + bhh[r];
    }
    if (idx < 2048) flags[idx] = 0u;
}

// W_out fp32 -> bf16 (separate: its 196MB stream stays off the latency path).
__global__ void prep_wout(const float* __restrict__ Wout, u16* __restrict__ Wo) {
    long long i = (long long)(blockIdx.x) * 256 + threadIdx.x;   // x4 elements each
    f32x4 v = *(const f32x4*)(Wout + i * 4);
    uint2 o;
    o.x = (uint32_t)f2bf(v[0]) | ((uint32_t)f2bf(v[1]) << 16);
    o.y = (uint32_t)f2bf(v[2]) | ((uint32_t)f2bf(v[3]) << 16);
    *(uint2*)(Wo + i * 4) = o;
}

// ---------------------------------------------------------------------------
// Init: h0 = enc @ W_h^T (bf16), c0 = enc @ W_c^T (fp32).
// ---------------------------------------------------------------------------
__global__ void init_hc(const float* __restrict__ enc, const float* __restrict__ Wh,
                        const float* __restrict__ Wcp, u16* __restrict__ h0,
                        float* __restrict__ c0) {
    int gwid = blockIdx.x * 4 + (threadIdx.x >> 6);   // 2048 waves
    int lane = threadIdx.x & 63;
    int sel = gwid >> 10;                // 0: h, 1: c
    int j = gwid & 1023;
    const float* W = sel ? Wcp : Wh;
    const float* wrow = W + (size_t)j * H_;
    f32x4 wv[4];
#pragma unroll
    for (int it = 0; it < 4; ++it)
        wv[it] = *(const f32x4*)(wrow + it * 256 + lane * 4);
#pragma unroll 2
    for (int b = 0; b < B_; ++b) {
        const float* erow = enc + (size_t)b * H_;
        float acc = 0.f;
#pragma unroll
        for (int it = 0; it < 4; ++it) {
            f32x4 ev = *(const f32x4*)(erow + it * 256 + lane * 4);
            acc += wv[it][0] * ev[0] + wv[it][1] * ev[1] + wv[it][2] * ev[2] + wv[it][3] * ev[3];
        }
#pragma unroll
        for (int s = 32; s >= 1; s >>= 1) acc += __shfl_xor(acc, s, 64);
        if (lane == 0) {
            if (sel) c0[(size_t)b * H_ + j] = acc;
            else     h0[(size_t)b * H_ + j] = f2bf(acc);
        }
    }
}

// ---------------------------------------------------------------------------
// FUSED kernel: blocks 0..63 = persistent LSTM recurrence; blocks 64..2063 =
// gated output GEMM (256x256 8-phase, m-tile = 32t x 8b). Flags are
// line-spread (flags[bid*32], 128B apart) to kill poll-storm serialization.
// ---------------------------------------------------------------------------
__global__ __launch_bounds__(512, 2) void fused_all(
    const u16* __restrict__ Wc, const float* __restrict__ wx,
    const float* __restrict__ biasc, const u16* __restrict__ h0,
    const float* __restrict__ c0, const float* __restrict__ y,
    u16* __restrict__ A, unsigned* __restrict__ flags,
    const u16* __restrict__ Wo, const float* __restrict__ bout,
    float* __restrict__ out) {
    __shared__ __align__(16) u16 sb[65536];   // 128KB pool (both roles)

    int tid = threadIdx.x;
    int lane = tid & 63;

    if (blockIdx.x < NBLK_REC) {
        // ================= recurrence =====================================
        float* red = (float*)sb;             // [8][64*33] = 16896 f
        float* cs  = red + 8 * 2112;         // [16][33]
        float* wxs = cs + 16 * 33;           // [64]
        float* bcs = wxs + 64;               // [64]
        float* ys  = bcs + 64;               // [32][129]

        int kw = tid >> 6;                   // wave id = K-slice
        int bid = blockIdx.x;
        int j0 = bid * 16;
        int jl = lane & 15;
        int kc = (lane >> 4) * 8;
        int jlx = tid & 15, pb = tid >> 4;   // pointwise: 1 (j,b) per thread

        short8 afr[4][4];
        {
            const u16* abase = Wc + (size_t)(j0 + jl) * H_ + kw * 128 + kc;
#pragma unroll
            for (int g = 0; g < 4; ++g)
#pragma unroll
                for (int ks = 0; ks < 4; ++ks)
                    afr[g][ks] = *(const short8*)(abase + (size_t)g * H_ * H_ + ks * 32);
        }
#pragma unroll
        for (int g = 0; g < 4; ++g)
#pragma unroll
            for (int ks = 0; ks < 4; ++ks)
                asm volatile("" : "+v"(afr[g][ks]));   // pin: defeat remat

        if (tid < 64) {
            int g = tid >> 4, qq = tid & 15;
            wxs[tid] = wx[(size_t)g * H_ + j0 + qq];
            bcs[tid] = biasc[(size_t)g * H_ + j0 + qq];
        }
#pragma unroll
        for (int i = tid; i < B_ * T_; i += 512)
            ys[(i >> 7) * 129 + (i & 127)] = y[i];
        cs[jlx * 33 + pb] = c0[(size_t)pb * H_ + j0 + jlx];
        __syncthreads();

        for (int t = 0; t < T_; ++t) {
            const u16* hp = (t == 0) ? h0 : (A + (size_t)(t - 1) * B_ * H_);

            if (t > 0) {
                // per-wave slice wait: 8 producers, each on its own 128B line
                const unsigned* fp = &flags[(kw * 8 + (lane & 7)) * 32];
                unsigned target = (unsigned)t;
                int guard = 0;
                for (;;) {
                    unsigned v = __hip_atomic_load(fp, __ATOMIC_RELAXED, __HIP_MEMORY_SCOPE_AGENT);
                    if (__all(v >= target)) break;
                    if (++guard > 20000000) break;
                }
                __atomic_signal_fence(__ATOMIC_ACQUIRE);
            }

            short8 bf0[4], bf1[4];
            {
                const u16* hb = hp + (size_t)jl * H_ + kw * 128 + kc;
#pragma unroll
                for (int ks = 0; ks < 4; ++ks) {
                    bf0[ks] = *(const short8*)(hb + ks * 32);
                    bf1[ks] = *(const short8*)(hb + (size_t)16 * H_ + ks * 32);
                }
            }
            f32x4 acc[4][2] = {};
#pragma unroll
            for (int ks = 0; ks < 4; ++ks) {
#pragma unroll
                for (int g = 0; g < 4; ++g) {
                    acc[g][0] = __builtin_amdgcn_mfma_f32_16x16x32_bf16(afr[g][ks], bf0[ks], acc[g][0], 0, 0, 0);
                    acc[g][1] = __builtin_amdgcn_mfma_f32_16x16x32_bf16(afr[g][ks], bf1[ks], acc[g][1], 0, 0, 0);
                }
            }
            int r0 = (lane >> 4) * 4;
#pragma unroll
            for (int g = 0; g < 4; ++g)
#pragma unroll
                for (int bt = 0; bt < 2; ++bt)
#pragma unroll
                    for (int r = 0; r < 4; ++r)
                        red[kw * 2112 + (g * 16 + r0 + r) * 33 + bt * 16 + jl] = acc[g][bt][r];
            __syncthreads();   // red RAW

            // ---- pointwise: every thread does ONE (jlx, pb) ----
            {
                float yv = ys[pb * 129 + t];
                float pg[4];
#pragma unroll
                for (int g = 0; g < 4; ++g) {
                    int row = (g * 16 + jlx) * 33 + pb;
                    float sum = red[row];
#pragma unroll
                    for (int ww = 1; ww < 8; ++ww) sum += red[ww * 2112 + row];
                    pg[g] = sum + wxs[g * 16 + jlx] * yv + bcs[g * 16 + jlx];
                }
                float iv = sigmf(pg[0]);
                float fv = sigmf(pg[1]);
                float gv = tanh_f(pg[2]);
                float ov = sigmf(pg[3]);
                float cv = fv * cs[jlx * 33 + pb] + iv * gv;
                cs[jlx * 33 + pb] = cv;
                float hv = ov * tanh_f(cv);

                unsigned h16 = (unsigned)f2bf(hv);
                unsigned oth = (unsigned)__shfl((int)h16, lane + 1, 64);  // jlx+1 partner
                if (!(jlx & 1)) {
                    uint32_t pk = h16 | (oth << 16);
                    __hip_atomic_store((uint32_t*)(A + ((size_t)t * B_ + pb) * H_ + j0 + jlx),
                                       pk, __ATOMIC_RELAXED, __HIP_MEMORY_SCOPE_AGENT);
                }
            }
            // Barrier drains every thread's vmcnt -> h_t stores visible.
            __syncthreads();
            if (tid == 0)
                __hip_atomic_store(&flags[bid * 32], (unsigned)(t + 1),
                                   __ATOMIC_RELAXED, __HIP_MEMORY_SCOPE_AGENT);
        }
        return;
    }

    // ================= gated output GEMM ==================================
    int orig = blockIdx.x - NBLK_REC;         // 0..1999
    int tb = orig / 500;                      // gate group, dispatch-ascending
    int wp = orig - tb * 500;
    int xcd = wp & 7, rest = wp >> 3;         // m204 bijective swizzle (500=8*62+4)
    int wg = (xcd < 4 ? xcd * 63 : 252 + (xcd - 4) * 62) + rest;
    int bb = wg / 125;                        // 0..3
    int nb = wg - bb * 125;                   // 0..124
    int n0g = nb << 8;

    int wid = tid >> 6;
    int wm = wid >> 2, wn = wid & 3;
    int jl = lane & 15, kq = lane >> 4;

    f32x4 acc[8][4] = {};

    // stage half-tile h (0=A0,1=A1,2=B0,3=B1) of K-tile `tile`
    auto stage = [&](int tile, int h) {
        u16* dst = sb + ((tile & 1) << 15) + (h << 13) + tid * 8;
#pragma unroll
        for (int ld = 0; ld < 2; ++ld) {
            int p = tid + (ld << 9);
            int row = p >> 3;
            int c16 = (p & 7) ^ (row & 7);        // inverse-swizzled source
            const u16* src;
            if (h < 2)
                src = A + ((size_t)(tb * 32 + (row & 31)) * B_
                           + (size_t)(bb * 8 + h * 4 + (row >> 5))) * H_
                        + tile * 64 + c16 * 8;
            else
                src = Wo + (size_t)(n0g + ((h - 2) << 7) + row) * H_
                         + tile * 64 + c16 * 8;
            gload16(src, dst + (ld << 12));
        }
    };

    // pre-gate: warm the B panels of tile 0 (Wo ready from prep_wout)
    stage(0, 2); stage(0, 3);

    // ---- gate: wave 0 polls all 64 producer lines; others park ----
    if (wid == 0) {
        unsigned target = (unsigned)((tb + 1) * 32);
        const unsigned* fp = &flags[lane * 32];
        int guard = 0;
        for (;;) {
            unsigned v = __hip_atomic_load(fp, __ATOMIC_RELAXED, __HIP_MEMORY_SCOPE_AGENT);
            if (__all(v >= target)) break;
            __builtin_amdgcn_s_sleep(32);
            if (++guard > 20000000) break;   // hang-safety
        }
        __atomic_signal_fence(__ATOMIC_ACQUIRE);
    }
    __builtin_amdgcn_s_barrier();

    // ---- prologue: A of tile0 + A0,B0 of tile1; leave 4 in flight ----
    stage(0, 0); stage(0, 1); stage(1, 0); stage(1, 2);
    asm volatile("s_waitcnt vmcnt(4)" ::: "memory");
    __builtin_amdgcn_s_barrier();

    const int NT = 16;   // K/64
    for (int tile = 0; tile < NT; ++tile) {
        const u16* buf = sb + ((tile & 1) << 15);
#pragma unroll
        for (int q = 0; q < 4; ++q) {
            const int mh = q >> 1, nh = q & 1;
            short8 af[4][2], bfr[2][2];
            const u16* bufA = buf + (mh << 13);
            const u16* bufB = buf + (1 << 14) + (nh << 13);
#pragma unroll
            for (int i = 0; i < 4; ++i) {
                int row = wm * 64 + (i << 4) + jl;
                int rx = (row & 7) << 3;
#pragma unroll
                for (int k2 = 0; k2 < 2; ++k2)
                    af[i][k2] = *(const short8*)(bufA + row * 64 + (((k2 << 5) + (kq << 3)) ^ rx));
            }
#pragma unroll
            for (int i = 0; i < 2; ++i) {
                int row = wn * 32 + (i << 4) + jl;
                int rx = (row & 7) << 3;
#pragma unroll
                for (int k2 = 0; k2 < 2; ++k2)
                    bfr[i][k2] = *(const short8*)(bufB + row * 64 + (((k2 << 5) + (kq << 3)) ^ rx));
            }
            if (q == 0) { if (tile + 1 < NT) stage(tile + 1, 1); }
            if (q == 1) { if (tile + 1 < NT) stage(tile + 1, 3); }
            if (q == 2) { if (tile + 2 < NT) stage(tile + 2, 0); }
            if (q == 3) { if (tile + 2 < NT) stage(tile + 2, 2); }

            asm volatile("" ::: "memory");
            __builtin_amdgcn_s_barrier();
            asm volatile("" ::: "memory");
            __builtin_amdgcn_s_setprio(1);
#pragma unroll
            for (int i = 0; i < 4; ++i)
#pragma unroll
                for (int jn = 0; jn < 2; ++jn)
#pragma unroll
                    for (int k2 = 0; k2 < 2; ++k2)
                        acc[mh * 4 + i][nh * 2 + jn] =
                            __builtin_amdgcn_mfma_f32_16x16x32_bf16(
                                af[i][k2], bfr[jn][k2], acc[mh * 4 + i][nh * 2 + jn], 0, 0, 0);
            __builtin_amdgcn_s_setprio(0);
            if (q == 3) {
                if (tile < 14) asm volatile("s_waitcnt vmcnt(4)" ::: "memory");
                else           asm volatile("s_waitcnt vmcnt(0)" ::: "memory");
            }
            asm volatile("" ::: "memory");
            __builtin_amdgcn_s_barrier();
        }
    }

    // ---- epilogue: per-wave LDS transpose to [n][b][t], 64B t-runs ----
    __syncthreads();
    float* wsl = (float*)sb + wid * 2048;     // 16n x 4b x 32t per wave
#pragma unroll
    for (int nt = 0; nt < 4; ++nt) {
        {
            int n = n0g + ((nt >> 1) << 7) + wn * 32 + ((nt & 1) << 4) + jl;
            float bias = bout[n];
#pragma unroll
            for (int mt = 0; mt < 8; ++mt) {
                int mh = mt >> 2, i = mt & 3;
                int b2 = mh * 2 + (i >> 1);
                int g = ((i & 1) << 2) + kq;       // t-group 0..7
                f32x4 v = acc[mt][nt];
                v[0] += bias; v[1] += bias; v[2] += bias; v[3] += bias;
                *(f32x4*)(wsl + jl * 128 + b2 * 32 + ((g ^ (jl & 7)) << 2)) = v;
            }
        }
#pragma unroll
        for (int rr = 0; rr < 2; ++rr) {
            int flat = lane * 2 + rr;              // 0..127
            int jr = flat >> 3;                    // n_loc 0..15
            int b2r = (flat >> 1) & 3;
            int h2 = flat & 1;                     // t half (0..15 / 16..31)
            int n2 = n0g + ((nt >> 1) << 7) + wn * 32 + ((nt & 1) << 4) + jr;
            int bo = bb * 8 + (b2r >> 1) * 4 + wm * 2 + (b2r & 1);
            int t0 = tb * 32 + h2 * 16;
            float* dst = out + ((size_t)bo * V_ + n2) * T_ + t0;
            const float* sp = wsl + jr * 128 + b2r * 32;
#pragma unroll
            for (int gg = 0; gg < 4; ++gg) {
                int g2 = h2 * 4 + gg;
                f32x4 v = *(const f32x4*)(sp + ((g2 ^ (jr & 7)) << 2));
                *(f32x4*)(dst + (gg << 2)) = v;
            }
        }
    }
}

// ---------------------------------------------------------------------------
extern "C" void kernel_launch(void* const* d_in, const int* in_sizes, int n_in,
                              void* d_out, int out_size, void* d_ws, size_t ws_size,
                              hipStream_t stream) {
    const float* y    = (const float*)d_in[0];   // [B,T]
    const float* enc  = (const float*)d_in[1];   // [B,H]
    const float* Wh   = (const float*)d_in[2];   // [H,H]
    const float* Wcp  = (const float*)d_in[3];   // [H,H]
    const float* Wih  = (const float*)d_in[4];   // [4H,1+H]
    const float* Whh  = (const float*)d_in[5];   // [4H,H]
    const float* bih  = (const float*)d_in[6];   // [4H]
    const float* bhh  = (const float*)d_in[7];   // [4H]
    const float* Wout = (const float*)d_in[8];   // [V,H]
    const float* bout = (const float*)d_in[9];   // [V]

    uint8_t* ws = (uint8_t*)d_ws;
    u16*  Wcomb = (u16*)ws;                                   // 8,388,608 B
    u16*  Wo    = (u16*)(ws + 8388608);                       // 65,536,000 B
    float* wx    = (float*)(ws + 8388608 + 65536000);
    float* biasc = wx + 4096;
    u16*  h0    = (u16*)(biasc + 4096);
    float* c     = (float*)(h0 + 32 * 1024);
    u16*  A     = (u16*)(c + 32 * 1024);                      // [T][B][H] bf16
    unsigned* flags = (unsigned*)(A + (size_t)4096 * 1024);   // 2048*4 B (line-spread)

    prep_w<<<16384, 256, 0, stream>>>(Wih, Whh, bih, bhh, Wcomb, wx, biasc, flags);
    prep_wout<<<32000, 256, 0, stream>>>(Wout, Wo);
    init_hc<<<512, 256, 0, stream>>>(enc, Wh, Wcp, h0, c);

    fused_all<<<NBLK_REC + 2000, 512, 0, stream>>>(
        Wcomb, wx, biasc, h0, c, y, A, flags, Wo, bout, (float*)d_out);
}